// Round 1
// baseline (1835.090 us; speedup 1.0000x reference)
//
#include <hip/hip_runtime.h>
#include <hip/hip_bf16.h>
#include <math.h>

#define N_NODES 100000
#define N_EDGES 1200000
#define N_GRAPHS 512

// ---- float <-> monotonic unsigned (for atomicMax on floats) ----
__device__ __forceinline__ unsigned f2ord(float f) {
  unsigned u = __float_as_uint(f);
  return (u & 0x80000000u) ? ~u : (u | 0x80000000u);
}
__device__ __forceinline__ float ord2f(unsigned u) {
  return (u & 0x80000000u) ? __uint_as_float(u & 0x7fffffffu) : __uint_as_float(~u);
}

__global__ void init_pool_kernel(float* gsum, unsigned* gmax, int* gcnt) {
  int i = blockIdx.x * blockDim.x + threadIdx.x;
  if (i < N_GRAPHS * 64) {
    gsum[i] = 0.0f;
    gmax[i] = 0x407FFFFFu;  // f2ord(-1.0f); elu outputs are > -1, so safe identity
  }
  if (i < N_GRAPHS) gcnt[i] = 0;
}

// h0 = x @ W_emb + b_emb   (x: [N,7], W: [7,64])
__global__ void embed_kernel(const float* __restrict__ x,
                             const float* __restrict__ W,
                             const float* __restrict__ b,
                             float* __restrict__ h) {
  __shared__ float Ws[7 * 64];
  __shared__ float bs[64];
  int t = threadIdx.x;
  for (int i = t; i < 7 * 64; i += 256) Ws[i] = W[i];
  if (t < 64) bs[t] = b[t];
  __syncthreads();
  int gid = blockIdx.x * 256 + t;          // one thread per (node, feature)
  int n = gid >> 6, f = gid & 63;
  const float* xr = x + n * 7;             // wave-uniform row -> cached/broadcast
  float acc = bs[f];
#pragma unroll
  for (int k = 0; k < 7; ++k) acc = fmaf(xr[k], Ws[k * 64 + f], acc);
  h[gid] = acc;
}

// agg[dst] += h[src]  -- one wave per edge, lane = feature
__global__ void scatter_kernel(const float* __restrict__ h,
                               const int* __restrict__ src,
                               const int* __restrict__ dst,
                               float* __restrict__ agg) {
  int lane = threadIdx.x & 63;
  int wave = (blockIdx.x * blockDim.x + threadIdx.x) >> 6;
  int nwaves = (gridDim.x * blockDim.x) >> 6;
  for (int e = wave; e < N_EDGES; e += nwaves) {
    int s = src[e];
    int d = dst[e];
    float v = h[(size_t)s * 64 + lane];
    atomicAdd(&agg[(size_t)d * 64 + lane], v);
  }
}

// h = elu( relu( ((1+eps)h + agg) @ W1 + b1 ) @ W2 + b2 )  (in place)
// one wave per node; lane = feature. Weights staged in LDS (~65 KB -> 2 blk/CU).
__launch_bounds__(256)
__global__ void gin_mlp_kernel(float* __restrict__ h,
                               const float* __restrict__ agg,
                               const float* __restrict__ eps_p,
                               const float* __restrict__ W1,
                               const float* __restrict__ b1,
                               const float* __restrict__ W2,
                               const float* __restrict__ b2) {
  __shared__ float W1s[64 * 128];
  __shared__ float W2s[128 * 64];
  __shared__ float b1s[128];
  __shared__ float b2s[64];
  int t = threadIdx.x;
  for (int i = t; i < 64 * 128; i += 256) W1s[i] = W1[i];
  for (int i = t; i < 128 * 64; i += 256) W2s[i] = W2[i];
  if (t < 128) b1s[t] = b1[t];
  if (t < 64) b2s[t] = b2[t];
  __syncthreads();
  float epsv = 1.0f + eps_p[0];
  int lane = t & 63;
  int wave = (blockIdx.x * 256 + t) >> 6;
  int nwaves = gridDim.x * 4;
  for (int n = wave; n < N_NODES; n += nwaves) {
    float in = fmaf(epsv, h[(size_t)n * 64 + lane], agg[(size_t)n * 64 + lane]);
    // GEMM1: t[128] = relu(in @ W1 + b1); lane holds cols {lane, lane+64}
    float tlo = b1s[lane], thi = b1s[64 + lane];
#pragma unroll 16
    for (int k = 0; k < 64; ++k) {
      float a = __shfl(in, k);  // broadcast in_k (register path, wave-safe)
      tlo = fmaf(a, W1s[k * 128 + lane], tlo);
      thi = fmaf(a, W1s[k * 128 + 64 + lane], thi);
    }
    tlo = fmaxf(tlo, 0.0f);
    thi = fmaxf(thi, 0.0f);
    // GEMM2: out[64] = t @ W2 + b2
    float o = b2s[lane];
#pragma unroll 16
    for (int k = 0; k < 64; ++k)
      o = fmaf(__shfl(tlo, k), W2s[k * 64 + lane], o);
#pragma unroll 16
    for (int k = 0; k < 64; ++k)
      o = fmaf(__shfl(thi, k), W2s[(64 + k) * 64 + lane], o);
    // elu (jax.nn.elu uses expm1)
    h[(size_t)n * 64 + lane] = (o > 0.0f) ? o : expm1f(o);
  }
}

// per-graph sum/max/count; batch is sorted, so each wave scans a contiguous
// chunk and accumulates in registers, flushing atomics only on graph change.
__global__ void pool_kernel(const float* __restrict__ h,
                            const int* __restrict__ batch,
                            float* gsum, unsigned* gmax, int* gcnt) {
  int lane = threadIdx.x & 63;
  int wave = (blockIdx.x * blockDim.x + threadIdx.x) >> 6;
  int nwaves = (gridDim.x * blockDim.x) >> 6;
  int chunk = (N_NODES + nwaves - 1) / nwaves;
  int n0 = wave * chunk;
  int n1 = min(n0 + chunk, N_NODES);
  if (n0 >= N_NODES) return;
  int cur = batch[n0];
  float s = 0.0f, m = -2.0f;
  int cnt = 0;
  for (int n = n0; n < n1; ++n) {
    int g = batch[n];
    if (g != cur) {
      atomicAdd(&gsum[cur * 64 + lane], s);
      atomicMax(&gmax[cur * 64 + lane], f2ord(m));
      if (lane == 0) atomicAdd(&gcnt[cur], cnt);
      cur = g; s = 0.0f; m = -2.0f; cnt = 0;
    }
    float v = h[(size_t)n * 64 + lane];
    s += v;
    m = fmaxf(m, v);
    ++cnt;
  }
  atomicAdd(&gsum[cur * 64 + lane], s);
  atomicMax(&gmax[cur * 64 + lane], f2ord(m));
  if (lane == 0) atomicAdd(&gcnt[cur], cnt);
}

// out = relu([mean|max] @ Wc1 + bc1) @ Wc2 + bc2 ; one 64-thread block / graph
__global__ void cls_kernel(const float* __restrict__ gsum,
                           const unsigned* __restrict__ gmax,
                           const int* __restrict__ gcnt,
                           const float* __restrict__ Wc1,
                           const float* __restrict__ bc1,
                           const float* __restrict__ Wc2,
                           const float* __restrict__ bc2,
                           float* __restrict__ out) {
  __shared__ float gv[128];
  __shared__ float tv[64];
  int g = blockIdx.x, l = threadIdx.x;
  float cnt = fmaxf((float)gcnt[g], 1.0f);
  gv[l] = gsum[g * 64 + l] / cnt;
  gv[64 + l] = ord2f(gmax[g * 64 + l]);
  __syncthreads();
  float acc = bc1[l];
#pragma unroll 8
  for (int k = 0; k < 128; ++k) acc = fmaf(gv[k], Wc1[k * 64 + l], acc);
  tv[l] = fmaxf(acc, 0.0f);
  __syncthreads();
  if (l < 10) {
    float o = bc2[l];
#pragma unroll
    for (int k = 0; k < 64; ++k) o = fmaf(tv[k], Wc2[k * 10 + l], o);
    out[g * 10 + l] = o;
  }
}

extern "C" void kernel_launch(void* const* d_in, const int* in_sizes, int n_in,
                              void* d_out, int out_size, void* d_ws, size_t ws_size,
                              hipStream_t stream) {
  const float* x     = (const float*)d_in[0];
  const int*   ei    = (const int*)d_in[1];
  const int*   batch = (const int*)d_in[2];
  const float* W_emb = (const float*)d_in[3];
  const float* b_emb = (const float*)d_in[4];
  const float* eps1  = (const float*)d_in[5];
  const float* W1a   = (const float*)d_in[6];
  const float* b1a   = (const float*)d_in[7];
  const float* W1b   = (const float*)d_in[8];
  const float* b1b   = (const float*)d_in[9];
  const float* eps2  = (const float*)d_in[10];
  const float* W2a   = (const float*)d_in[11];
  const float* b2a   = (const float*)d_in[12];
  const float* W2b   = (const float*)d_in[13];
  const float* b2b   = (const float*)d_in[14];
  const float* eps3  = (const float*)d_in[15];
  const float* W3a   = (const float*)d_in[16];
  const float* b3a   = (const float*)d_in[17];
  const float* W3b   = (const float*)d_in[18];
  const float* b3b   = (const float*)d_in[19];
  const float* Wc1   = (const float*)d_in[20];
  const float* bc1   = (const float*)d_in[21];
  const float* Wc2   = (const float*)d_in[22];
  const float* bc2   = (const float*)d_in[23];
  float* out = (float*)d_out;

  // workspace layout (f32 elements)
  float*    h    = (float*)d_ws;                       // 6.4M
  float*    agg  = h + (size_t)N_NODES * 64;           // 6.4M
  float*    gsum = agg + (size_t)N_NODES * 64;         // 32768
  unsigned* gmax = (unsigned*)(gsum + N_GRAPHS * 64);  // 32768
  int*      gcnt = (int*)(gmax + N_GRAPHS * 64);       // 512

  const int* src = ei;             // edge_index[0]
  const int* dst = ei + N_EDGES;   // edge_index[1]

  init_pool_kernel<<<(N_GRAPHS * 64 + 255) / 256, 256, 0, stream>>>(gsum, gmax, gcnt);
  embed_kernel<<<(N_NODES * 64) / 256, 256, 0, stream>>>(x, W_emb, b_emb, h);

  const float* epss[3] = {eps1, eps2, eps3};
  const float* Was[3]  = {W1a, W2a, W3a};
  const float* bas[3]  = {b1a, b2a, b3a};
  const float* Wbs[3]  = {W1b, W2b, W3b};
  const float* bbs[3]  = {b1b, b2b, b3b};

  for (int L = 0; L < 3; ++L) {
    hipMemsetAsync(agg, 0, (size_t)N_NODES * 64 * sizeof(float), stream);
    scatter_kernel<<<2048, 256, 0, stream>>>(h, src, dst, agg);
    gin_mlp_kernel<<<1024, 256, 0, stream>>>(h, agg, epss[L], Was[L], bas[L],
                                             Wbs[L], bbs[L]);
  }

  pool_kernel<<<512, 256, 0, stream>>>(h, batch, gsum, gmax, gcnt);
  cls_kernel<<<N_GRAPHS, 64, 0, stream>>>(gsum, gmax, gcnt, Wc1, bc1, Wc2, bc2, out);
}

// Round 2
// 1072.349 us; speedup vs baseline: 1.7113x; 1.7113x over previous
//
#include <hip/hip_runtime.h>
#include <hip/hip_bf16.h>
#include <math.h>

#define N_NODES 100000
#define N_EDGES 1200000
#define N_GRAPHS 512

typedef __bf16 bf16x8 __attribute__((ext_vector_type(8)));
typedef float f32x4 __attribute__((ext_vector_type(4)));

// ---- float <-> monotonic unsigned (for atomicMax on floats) ----
__device__ __forceinline__ unsigned f2ord(float f) {
  unsigned u = __float_as_uint(f);
  return (u & 0x80000000u) ? ~u : (u | 0x80000000u);
}
__device__ __forceinline__ float ord2f(unsigned u) {
  return (u & 0x80000000u) ? __uint_as_float(u & 0x7fffffffu) : __uint_as_float(~u);
}

__global__ void init_pool_kernel(float* gsum, unsigned* gmax, int* gcnt) {
  int i = blockIdx.x * blockDim.x + threadIdx.x;
  if (i < N_GRAPHS * 64) {
    gsum[i] = 0.0f;
    gmax[i] = 0x407FFFFFu;  // f2ord(-1.0f); elu outputs are > -1, safe identity
  }
  if (i < N_GRAPHS) gcnt[i] = 0;
}

// h0 = x @ W_emb + b_emb   (x: [N,7], W: [7,64])
__global__ void embed_kernel(const float* __restrict__ x,
                             const float* __restrict__ W,
                             const float* __restrict__ b,
                             float* __restrict__ h) {
  __shared__ float Ws[7 * 64];
  __shared__ float bs[64];
  int t = threadIdx.x;
  for (int i = t; i < 7 * 64; i += 256) Ws[i] = W[i];
  if (t < 64) bs[t] = b[t];
  __syncthreads();
  int gid = blockIdx.x * 256 + t;
  int n = gid >> 6, f = gid & 63;
  const float* xr = x + n * 7;
  float acc = bs[f];
#pragma unroll
  for (int k = 0; k < 7; ++k) acc = fmaf(xr[k], Ws[k * 64 + f], acc);
  h[gid] = acc;
}

// agg[dst] += h[src]  -- one wave per edge, lane = feature
__global__ void scatter_kernel(const float* __restrict__ h,
                               const int* __restrict__ src,
                               const int* __restrict__ dst,
                               float* __restrict__ agg) {
  int lane = threadIdx.x & 63;
  int wave = (blockIdx.x * blockDim.x + threadIdx.x) >> 6;
  int nwaves = (gridDim.x * blockDim.x) >> 6;
  for (int e = wave; e < N_EDGES; e += nwaves) {
    int s = src[e];
    int d = dst[e];
    float v = h[(size_t)s * 64 + lane];
    atomicAdd(&agg[(size_t)d * 64 + lane], v);
  }
}

// Pre-permute f32 weights into bf16 MFMA B-fragment order.
// Wa [64,128] -> WpA[ ((nt*2+kt)*4+kc)*128 + c*8 + j ] = Wa[(kt*32+kc*8+j)*128 + nt*16+c]
// Wb [128,64] -> WpB[ ((nt2*4+kt)*4+kc)*128 + c*8 + j ] = Wb[(kt*32+kc*8+j)*64 + nt2*16+c]
__global__ void convert_w_kernel(const float* __restrict__ Wa,
                                 const float* __restrict__ Wb,
                                 __bf16* __restrict__ WpA,
                                 __bf16* __restrict__ WpB) {
  int o = blockIdx.x * 256 + threadIdx.x;  // 0..16383
  if (o < 8192) {
    int j = o & 7, c = (o >> 3) & 15, kc = (o >> 7) & 3, kt = (o >> 9) & 1, nt = o >> 10;
    WpA[o] = (__bf16)Wa[(kt * 32 + kc * 8 + j) * 128 + nt * 16 + c];
  } else {
    int q = o - 8192;
    int j = q & 7, c = (q >> 3) & 15, kc = (q >> 7) & 3, kt = (q >> 9) & 3, nt2 = q >> 11;
    WpB[q] = (__bf16)Wb[(kt * 32 + kc * 8 + j) * 64 + nt2 * 16 + c];
  }
}

// Fused GIN MLP via MFMA: h = elu( relu( ((1+eps)h + agg) @ W1 + b1 ) @ W2 + b2 )
// One block = 64 nodes; 4 waves, wave w owns rows w*16..w*16+15.
// A tile [64][72] bf16 (pad->pitch 144B, 16B aligned); hidden [64][136] bf16.
__launch_bounds__(256)
__global__ void gin_mfma_kernel(float* __restrict__ h,
                                const float* __restrict__ agg,
                                const float* __restrict__ eps_p,
                                const __bf16* __restrict__ W1p,
                                const float* __restrict__ b1,
                                const __bf16* __restrict__ W2p,
                                const float* __restrict__ b2) {
  __shared__ __bf16 As[64 * 72];
  __shared__ __bf16 Hs[64 * 136];
  __shared__ __bf16 W1s[8192];
  __shared__ __bf16 W2s[8192];
  __shared__ float b1s[128];
  __shared__ float b2s[64];
  int t = threadIdx.x;
  // stage weights (bf16, fragment order) via 16B vector copies
  {
    const uint4* s1 = (const uint4*)W1p;
    uint4* d1 = (uint4*)W1s;
    const uint4* s2 = (const uint4*)W2p;
    uint4* d2 = (uint4*)W2s;
    for (int i = t; i < 1024; i += 256) d1[i] = s1[i];
    for (int i = t; i < 1024; i += 256) d2[i] = s2[i];
  }
  if (t < 128) b1s[t] = b1[t];
  if (t < 64) b2s[t] = b2[t];
  float epsv = 1.0f + eps_p[0];
  int n0b = blockIdx.x * 64;
  // stage A = (1+eps)*h + agg  (bf16)
#pragma unroll
  for (int i = 0; i < 16; ++i) {
    int e = t + i * 256;
    int row = e >> 6, col = e & 63;
    int g = n0b + row;
    float v = 0.0f;
    if (g < N_NODES) v = fmaf(epsv, h[(size_t)g * 64 + col], agg[(size_t)g * 64 + col]);
    As[row * 72 + col] = (__bf16)v;
  }
  __syncthreads();

  int lane = t & 63, wv = t >> 6;
  int c = lane & 15, kc = lane >> 4;
  int m0 = wv * 16;

  // GEMM1: [16x64] @ [64x128]
  bf16x8 a1_0 = *(const bf16x8*)&As[(m0 + c) * 72 + 0 * 32 + kc * 8];
  bf16x8 a1_1 = *(const bf16x8*)&As[(m0 + c) * 72 + 1 * 32 + kc * 8];
  f32x4 acc1[8];
#pragma unroll
  for (int nt = 0; nt < 8; ++nt) {
    float bv = b1s[nt * 16 + c];
    f32x4 acc = {bv, bv, bv, bv};
    bf16x8 bf0 = *(const bf16x8*)&W1s[(nt * 2 + 0) * 512 + kc * 128 + c * 8];
    bf16x8 bf1 = *(const bf16x8*)&W1s[(nt * 2 + 1) * 512 + kc * 128 + c * 8];
    acc = __builtin_amdgcn_mfma_f32_16x16x32_bf16(a1_0, bf0, acc, 0, 0, 0);
    acc = __builtin_amdgcn_mfma_f32_16x16x32_bf16(a1_1, bf1, acc, 0, 0, 0);
    acc1[nt] = acc;
  }
  // relu -> bf16 hidden tile (wave-private rows)
#pragma unroll
  for (int nt = 0; nt < 8; ++nt) {
#pragma unroll
    for (int r = 0; r < 4; ++r) {
      Hs[(m0 + kc * 4 + r) * 136 + nt * 16 + c] = (__bf16)fmaxf(acc1[nt][r], 0.0f);
    }
  }
  __syncthreads();

  // GEMM2: [16x128] @ [128x64]
  bf16x8 a2[4];
#pragma unroll
  for (int kt = 0; kt < 4; ++kt)
    a2[kt] = *(const bf16x8*)&Hs[(m0 + c) * 136 + kt * 32 + kc * 8];
#pragma unroll
  for (int nt2 = 0; nt2 < 4; ++nt2) {
    float bv = b2s[nt2 * 16 + c];
    f32x4 acc = {bv, bv, bv, bv};
#pragma unroll
    for (int kt = 0; kt < 4; ++kt) {
      bf16x8 bf = *(const bf16x8*)&W2s[(nt2 * 4 + kt) * 512 + kc * 128 + c * 8];
      acc = __builtin_amdgcn_mfma_f32_16x16x32_bf16(a2[kt], bf, acc, 0, 0, 0);
    }
#pragma unroll
    for (int r = 0; r < 4; ++r) {
      int g = n0b + m0 + kc * 4 + r;
      if (g < N_NODES) {
        float o = acc[r];
        h[(size_t)g * 64 + nt2 * 16 + c] = (o > 0.0f) ? o : expm1f(o);
      }
    }
  }
}

// per-graph sum/max/count; batch sorted -> wave scans contiguous chunk
__global__ void pool_kernel(const float* __restrict__ h,
                            const int* __restrict__ batch,
                            float* gsum, unsigned* gmax, int* gcnt) {
  int lane = threadIdx.x & 63;
  int wave = (blockIdx.x * blockDim.x + threadIdx.x) >> 6;
  int nwaves = (gridDim.x * blockDim.x) >> 6;
  int chunk = (N_NODES + nwaves - 1) / nwaves;
  int n0 = wave * chunk;
  int n1 = min(n0 + chunk, N_NODES);
  if (n0 >= N_NODES) return;
  int cur = batch[n0];
  float s = 0.0f, m = -2.0f;
  int cnt = 0;
  for (int n = n0; n < n1; ++n) {
    int g = batch[n];
    if (g != cur) {
      atomicAdd(&gsum[cur * 64 + lane], s);
      atomicMax(&gmax[cur * 64 + lane], f2ord(m));
      if (lane == 0) atomicAdd(&gcnt[cur], cnt);
      cur = g; s = 0.0f; m = -2.0f; cnt = 0;
    }
    float v = h[(size_t)n * 64 + lane];
    s += v;
    m = fmaxf(m, v);
    ++cnt;
  }
  atomicAdd(&gsum[cur * 64 + lane], s);
  atomicMax(&gmax[cur * 64 + lane], f2ord(m));
  if (lane == 0) atomicAdd(&gcnt[cur], cnt);
}

// out = relu([mean|max] @ Wc1 + bc1) @ Wc2 + bc2 ; one 64-thread block / graph
__global__ void cls_kernel(const float* __restrict__ gsum,
                           const unsigned* __restrict__ gmax,
                           const int* __restrict__ gcnt,
                           const float* __restrict__ Wc1,
                           const float* __restrict__ bc1,
                           const float* __restrict__ Wc2,
                           const float* __restrict__ bc2,
                           float* __restrict__ out) {
  __shared__ float gv[128];
  __shared__ float tv[64];
  int g = blockIdx.x, l = threadIdx.x;
  float cnt = fmaxf((float)gcnt[g], 1.0f);
  gv[l] = gsum[g * 64 + l] / cnt;
  gv[64 + l] = ord2f(gmax[g * 64 + l]);
  __syncthreads();
  float acc = bc1[l];
#pragma unroll 8
  for (int k = 0; k < 128; ++k) acc = fmaf(gv[k], Wc1[k * 64 + l], acc);
  tv[l] = fmaxf(acc, 0.0f);
  __syncthreads();
  if (l < 10) {
    float o = bc2[l];
#pragma unroll
    for (int k = 0; k < 64; ++k) o = fmaf(tv[k], Wc2[k * 10 + l], o);
    out[g * 10 + l] = o;
  }
}

extern "C" void kernel_launch(void* const* d_in, const int* in_sizes, int n_in,
                              void* d_out, int out_size, void* d_ws, size_t ws_size,
                              hipStream_t stream) {
  const float* x     = (const float*)d_in[0];
  const int*   ei    = (const int*)d_in[1];
  const int*   batch = (const int*)d_in[2];
  const float* W_emb = (const float*)d_in[3];
  const float* b_emb = (const float*)d_in[4];
  const float* eps1  = (const float*)d_in[5];
  const float* W1a   = (const float*)d_in[6];
  const float* b1a   = (const float*)d_in[7];
  const float* W1b   = (const float*)d_in[8];
  const float* b1b   = (const float*)d_in[9];
  const float* eps2  = (const float*)d_in[10];
  const float* W2a   = (const float*)d_in[11];
  const float* b2a   = (const float*)d_in[12];
  const float* W2b   = (const float*)d_in[13];
  const float* b2b   = (const float*)d_in[14];
  const float* eps3  = (const float*)d_in[15];
  const float* W3a   = (const float*)d_in[16];
  const float* b3a   = (const float*)d_in[17];
  const float* W3b   = (const float*)d_in[18];
  const float* b3b   = (const float*)d_in[19];
  const float* Wc1   = (const float*)d_in[20];
  const float* bc1   = (const float*)d_in[21];
  const float* Wc2   = (const float*)d_in[22];
  const float* bc2   = (const float*)d_in[23];
  float* out = (float*)d_out;

  // workspace layout (f32 elements)
  float*    h    = (float*)d_ws;                       // 6.4M f32
  float*    agg  = h + (size_t)N_NODES * 64;           // 6.4M f32
  float*    gsum = agg + (size_t)N_NODES * 64;         // 32768 f32
  unsigned* gmax = (unsigned*)(gsum + N_GRAPHS * 64);  // 32768
  int*      gcnt = (int*)(gmax + N_GRAPHS * 64);       // 512
  __bf16*   wp   = (__bf16*)(gcnt + 512);              // 3 layers x 2 x 8192 bf16

  const int* src = ei;             // edge_index[0]
  const int* dst = ei + N_EDGES;   // edge_index[1]

  const float* epss[3] = {eps1, eps2, eps3};
  const float* Was[3]  = {W1a, W2a, W3a};
  const float* bas[3]  = {b1a, b2a, b3a};
  const float* Wbs[3]  = {W1b, W2b, W3b};
  const float* bbs[3]  = {b1b, b2b, b3b};

  init_pool_kernel<<<(N_GRAPHS * 64 + 255) / 256, 256, 0, stream>>>(gsum, gmax, gcnt);
  for (int L = 0; L < 3; ++L)
    convert_w_kernel<<<64, 256, 0, stream>>>(Was[L], Wbs[L],
                                             wp + (size_t)L * 16384,
                                             wp + (size_t)L * 16384 + 8192);
  embed_kernel<<<(N_NODES * 64) / 256, 256, 0, stream>>>(x, W_emb, b_emb, h);

  for (int L = 0; L < 3; ++L) {
    hipMemsetAsync(agg, 0, (size_t)N_NODES * 64 * sizeof(float), stream);
    scatter_kernel<<<2048, 256, 0, stream>>>(h, src, dst, agg);
    gin_mfma_kernel<<<(N_NODES + 63) / 64, 256, 0, stream>>>(
        h, agg, epss[L], wp + (size_t)L * 16384, bas[L],
        wp + (size_t)L * 16384 + 8192, bbs[L]);
  }

  pool_kernel<<<512, 256, 0, stream>>>(h, batch, gsum, gmax, gcnt);
  cls_kernel<<<N_GRAPHS, 64, 0, stream>>>(gsum, gmax, gcnt, Wc1, bc1, Wc2, bc2, out);
}

// Round 3
// 575.446 us; speedup vs baseline: 3.1890x; 1.8635x over previous
//
#include <hip/hip_runtime.h>
#include <hip/hip_bf16.h>
#include <math.h>

#define N_NODES 100000
#define N_EDGES 1200000
#define N_GRAPHS 512

typedef __bf16 bf16x8 __attribute__((ext_vector_type(8)));
typedef float f32x4 __attribute__((ext_vector_type(4)));

// ---- float <-> monotonic unsigned (for atomicMax on floats) ----
__device__ __forceinline__ unsigned f2ord(float f) {
  unsigned u = __float_as_uint(f);
  return (u & 0x80000000u) ? ~u : (u | 0x80000000u);
}
__device__ __forceinline__ float ord2f(unsigned u) {
  return (u & 0x80000000u) ? __uint_as_float(u & 0x7fffffffu) : __uint_as_float(~u);
}

__global__ void init_pool_kernel(float* gsum, unsigned* gmax, int* gcnt) {
  int i = blockIdx.x * blockDim.x + threadIdx.x;
  if (i < N_GRAPHS * 64) {
    gsum[i] = 0.0f;
    gmax[i] = 0x407FFFFFu;  // f2ord(-1.0f); elu outputs are > -1, safe identity
  }
  if (i < N_GRAPHS) gcnt[i] = 0;
}

// ---------------- CSR build (once per call; shared by all 3 layers) ---------
__global__ void hist_kernel(const int* __restrict__ dst, int* __restrict__ deg) {
  int e = blockIdx.x * 256 + threadIdx.x;
  if (e < N_EDGES) atomicAdd(&deg[dst[e]], 1);
}

// per-256-tile sums
__global__ void scan_sums_kernel(const int* __restrict__ deg, int* __restrict__ bsum) {
  __shared__ int s[256];
  int t = threadIdx.x;
  int i = blockIdx.x * 256 + t;
  s[t] = (i < N_NODES) ? deg[i] : 0;
  __syncthreads();
  for (int o = 128; o > 0; o >>= 1) {
    if (t < o) s[t] += s[t + o];
    __syncthreads();
  }
  if (t == 0) bsum[blockIdx.x] = s[0];
}

// single-block exclusive scan of the 391 tile sums
__global__ void scan_bsums_kernel(const int* __restrict__ bsum, int* __restrict__ boff,
                                  int nb) {
  __shared__ int s[512];
  int t = threadIdx.x;
  int own = (t < nb) ? bsum[t] : 0;
  s[t] = own;
  __syncthreads();
  for (int o = 1; o < 512; o <<= 1) {
    int v = (t >= o) ? s[t - o] : 0;
    __syncthreads();
    s[t] += v;
    __syncthreads();
  }
  if (t < nb) boff[t] = s[t] - own;  // exclusive
}

// final: row_ptr[i] = boff[block] + exclusive_scan_in_tile; also init cursor
__global__ void scan_final_kernel(const int* __restrict__ deg,
                                  const int* __restrict__ boff,
                                  int* __restrict__ row_ptr,
                                  int* __restrict__ curw) {
  __shared__ int s[256];
  int t = threadIdx.x;
  int i = blockIdx.x * 256 + t;
  int own = (i < N_NODES) ? deg[i] : 0;
  s[t] = own;
  __syncthreads();
  for (int o = 1; o < 256; o <<= 1) {
    int v = (t >= o) ? s[t - o] : 0;
    __syncthreads();
    s[t] += v;
    __syncthreads();
  }
  if (i < N_NODES) {
    int excl = boff[blockIdx.x] + s[t] - own;
    row_ptr[i] = excl;
    curw[i] = excl;
  }
  if (i == 0) row_ptr[N_NODES] = N_EDGES;
}

__global__ void fill_csr_kernel(const int* __restrict__ src, const int* __restrict__ dst,
                                int* __restrict__ curw, int* __restrict__ ssrc) {
  int e = blockIdx.x * 256 + threadIdx.x;
  if (e < N_EDGES) {
    int p = atomicAdd(&curw[dst[e]], 1);
    ssrc[p] = src[e];
  }
}

// ---------------- dense pipeline ---------------------------------------------
// h0 = x @ W_emb + b_emb   (x: [N,7], W: [7,64])
__global__ void embed_kernel(const float* __restrict__ x,
                             const float* __restrict__ W,
                             const float* __restrict__ b,
                             float* __restrict__ h) {
  __shared__ float Ws[7 * 64];
  __shared__ float bs[64];
  int t = threadIdx.x;
  for (int i = t; i < 7 * 64; i += 256) Ws[i] = W[i];
  if (t < 64) bs[t] = b[t];
  __syncthreads();
  int gid = blockIdx.x * 256 + t;
  int n = gid >> 6, f = gid & 63;
  const float* xr = x + n * 7;
  float acc = bs[f];
#pragma unroll
  for (int k = 0; k < 7; ++k) acc = fmaf(xr[k], Ws[k * 64 + f], acc);
  h[gid] = acc;
}

// Pre-permute f32 weights into bf16 MFMA B-fragment order (same as round 2).
__global__ void convert_w_kernel(const float* __restrict__ Wa,
                                 const float* __restrict__ Wb,
                                 __bf16* __restrict__ WpA,
                                 __bf16* __restrict__ WpB) {
  int o = blockIdx.x * 256 + threadIdx.x;  // 0..16383
  if (o < 8192) {
    int j = o & 7, c = (o >> 3) & 15, kc = (o >> 7) & 3, kt = (o >> 9) & 1, nt = o >> 10;
    WpA[o] = (__bf16)Wa[(kt * 32 + kc * 8 + j) * 128 + nt * 16 + c];
  } else {
    int q = o - 8192;
    int j = q & 7, c = (q >> 3) & 15, kc = (q >> 7) & 3, kt = (q >> 9) & 3, nt2 = q >> 11;
    WpB[q] = (__bf16)Wb[(kt * 32 + kc * 8 + j) * 64 + nt2 * 16 + c];
  }
}

// Fused: agg gather (CSR) + GIN MLP via MFMA, h_out = elu(relu(A@W1+b1)@W2+b2),
// A = (1+eps)h_in + sum_{e in CSR(n)} h_in[src]. One block = 64 nodes, 4 waves;
// each wave owns rows wv*16..+15 end-to-end -> NO __syncthreads needed.
// Weights read from global (16 KB, L1-resident) to keep LDS at ~27 KB.
__launch_bounds__(256)
__global__ void gin_fused_kernel(const float* __restrict__ hin,
                                 float* __restrict__ hout,
                                 const int* __restrict__ row_ptr,
                                 const int* __restrict__ ssrc,
                                 const float* __restrict__ eps_p,
                                 const __bf16* __restrict__ W1p,
                                 const float* __restrict__ b1,
                                 const __bf16* __restrict__ W2p,
                                 const float* __restrict__ b2) {
  __shared__ __bf16 As[64 * 72];
  __shared__ __bf16 Hs[64 * 136];
  int t = threadIdx.x, lane = t & 63, wv = t >> 6;
  int c = lane & 15, kc = lane >> 4;
  int m0 = wv * 16;
  float epsv = 1.0f + eps_p[0];
  int n0b = blockIdx.x * 64;
  int n0w = n0b + m0;

  // row_ptr[n0w .. n0w+16] via lanes 0..16, broadcast by shfl
  int rp = row_ptr[min(n0w + min(lane, 16), N_NODES)];

  // stage A rows for this wave's 16 nodes
  for (int r = 0; r < 16; ++r) {
    int n = n0w + r;
    float acc = 0.0f;
    if (n < N_NODES) {
      acc = epsv * hin[(size_t)n * 64 + lane];
      int rs = __shfl(rp, r), re = __shfl(rp, r + 1);
      for (int base = rs; base < re; base += 64) {
        int cnt = min(64, re - base);
        int si = (lane < cnt) ? ssrc[base + lane] : 0;
        int j = 0;
        for (; j + 4 <= cnt; j += 4) {
          int s0 = __shfl(si, j), s1 = __shfl(si, j + 1);
          int s2 = __shfl(si, j + 2), s3 = __shfl(si, j + 3);
          float v0 = hin[(size_t)s0 * 64 + lane];
          float v1 = hin[(size_t)s1 * 64 + lane];
          float v2 = hin[(size_t)s2 * 64 + lane];
          float v3 = hin[(size_t)s3 * 64 + lane];
          acc += v0; acc += v1; acc += v2; acc += v3;
        }
        for (; j < cnt; ++j) {
          int s = __shfl(si, j);
          acc += hin[(size_t)s * 64 + lane];
        }
      }
    }
    As[(m0 + r) * 72 + lane] = (__bf16)acc;
  }

  // GEMM1: [16x64] @ [64x128]  (wave-private rows; lgkmcnt handled by compiler)
  bf16x8 a1_0 = *(const bf16x8*)&As[(m0 + c) * 72 + 0 * 32 + kc * 8];
  bf16x8 a1_1 = *(const bf16x8*)&As[(m0 + c) * 72 + 1 * 32 + kc * 8];
  f32x4 acc1[8];
#pragma unroll
  for (int nt = 0; nt < 8; ++nt) {
    float bv = b1[nt * 16 + c];
    f32x4 acc = {bv, bv, bv, bv};
    bf16x8 bf0 = *(const bf16x8*)&W1p[(nt * 2 + 0) * 512 + kc * 128 + c * 8];
    bf16x8 bf1 = *(const bf16x8*)&W1p[(nt * 2 + 1) * 512 + kc * 128 + c * 8];
    acc = __builtin_amdgcn_mfma_f32_16x16x32_bf16(a1_0, bf0, acc, 0, 0, 0);
    acc = __builtin_amdgcn_mfma_f32_16x16x32_bf16(a1_1, bf1, acc, 0, 0, 0);
    acc1[nt] = acc;
  }
  // relu -> bf16 hidden tile (wave-private rows)
#pragma unroll
  for (int nt = 0; nt < 8; ++nt) {
#pragma unroll
    for (int r = 0; r < 4; ++r) {
      Hs[(m0 + kc * 4 + r) * 136 + nt * 16 + c] = (__bf16)fmaxf(acc1[nt][r], 0.0f);
    }
  }

  // GEMM2: [16x128] @ [128x64]
  bf16x8 a2[4];
#pragma unroll
  for (int kt = 0; kt < 4; ++kt)
    a2[kt] = *(const bf16x8*)&Hs[(m0 + c) * 136 + kt * 32 + kc * 8];
#pragma unroll
  for (int nt2 = 0; nt2 < 4; ++nt2) {
    float bv = b2[nt2 * 16 + c];
    f32x4 acc = {bv, bv, bv, bv};
#pragma unroll
    for (int kt = 0; kt < 4; ++kt) {
      bf16x8 bf = *(const bf16x8*)&W2p[(nt2 * 4 + kt) * 512 + kc * 128 + c * 8];
      acc = __builtin_amdgcn_mfma_f32_16x16x32_bf16(a2[kt], bf, acc, 0, 0, 0);
    }
#pragma unroll
    for (int r = 0; r < 4; ++r) {
      int g = n0b + m0 + kc * 4 + r;
      if (g < N_NODES) {
        float o = acc[r];
        hout[(size_t)g * 64 + nt2 * 16 + c] = (o > 0.0f) ? o : expm1f(o);
      }
    }
  }
}

// per-graph sum/max/count; batch sorted -> wave scans contiguous chunk
__global__ void pool_kernel(const float* __restrict__ h,
                            const int* __restrict__ batch,
                            float* gsum, unsigned* gmax, int* gcnt) {
  int lane = threadIdx.x & 63;
  int wave = (blockIdx.x * blockDim.x + threadIdx.x) >> 6;
  int nwaves = (gridDim.x * blockDim.x) >> 6;
  int chunk = (N_NODES + nwaves - 1) / nwaves;
  int n0 = wave * chunk;
  int n1 = min(n0 + chunk, N_NODES);
  if (n0 >= N_NODES) return;
  int cur = batch[n0];
  float s = 0.0f, m = -2.0f;
  int cnt = 0;
  for (int n = n0; n < n1; ++n) {
    int g = batch[n];
    if (g != cur) {
      atomicAdd(&gsum[cur * 64 + lane], s);
      atomicMax(&gmax[cur * 64 + lane], f2ord(m));
      if (lane == 0) atomicAdd(&gcnt[cur], cnt);
      cur = g; s = 0.0f; m = -2.0f; cnt = 0;
    }
    float v = h[(size_t)n * 64 + lane];
    s += v;
    m = fmaxf(m, v);
    ++cnt;
  }
  atomicAdd(&gsum[cur * 64 + lane], s);
  atomicMax(&gmax[cur * 64 + lane], f2ord(m));
  if (lane == 0) atomicAdd(&gcnt[cur], cnt);
}

// out = relu([mean|max] @ Wc1 + bc1) @ Wc2 + bc2 ; one 64-thread block / graph
__global__ void cls_kernel(const float* __restrict__ gsum,
                           const unsigned* __restrict__ gmax,
                           const int* __restrict__ gcnt,
                           const float* __restrict__ Wc1,
                           const float* __restrict__ bc1,
                           const float* __restrict__ Wc2,
                           const float* __restrict__ bc2,
                           float* __restrict__ out) {
  __shared__ float gv[128];
  __shared__ float tv[64];
  int g = blockIdx.x, l = threadIdx.x;
  float cnt = fmaxf((float)gcnt[g], 1.0f);
  gv[l] = gsum[g * 64 + l] / cnt;
  gv[64 + l] = ord2f(gmax[g * 64 + l]);
  __syncthreads();
  float acc = bc1[l];
#pragma unroll 8
  for (int k = 0; k < 128; ++k) acc = fmaf(gv[k], Wc1[k * 64 + l], acc);
  tv[l] = fmaxf(acc, 0.0f);
  __syncthreads();
  if (l < 10) {
    float o = bc2[l];
#pragma unroll
    for (int k = 0; k < 64; ++k) o = fmaf(tv[k], Wc2[k * 10 + l], o);
    out[g * 10 + l] = o;
  }
}

extern "C" void kernel_launch(void* const* d_in, const int* in_sizes, int n_in,
                              void* d_out, int out_size, void* d_ws, size_t ws_size,
                              hipStream_t stream) {
  const float* x     = (const float*)d_in[0];
  const int*   ei    = (const int*)d_in[1];
  const int*   batch = (const int*)d_in[2];
  const float* W_emb = (const float*)d_in[3];
  const float* b_emb = (const float*)d_in[4];
  const float* eps1  = (const float*)d_in[5];
  const float* W1a   = (const float*)d_in[6];
  const float* b1a   = (const float*)d_in[7];
  const float* W1b   = (const float*)d_in[8];
  const float* b1b   = (const float*)d_in[9];
  const float* eps2  = (const float*)d_in[10];
  const float* W2a   = (const float*)d_in[11];
  const float* b2a   = (const float*)d_in[12];
  const float* W2b   = (const float*)d_in[13];
  const float* b2b   = (const float*)d_in[14];
  const float* eps3  = (const float*)d_in[15];
  const float* W3a   = (const float*)d_in[16];
  const float* b3a   = (const float*)d_in[17];
  const float* W3b   = (const float*)d_in[18];
  const float* b3b   = (const float*)d_in[19];
  const float* Wc1   = (const float*)d_in[20];
  const float* bc1   = (const float*)d_in[21];
  const float* Wc2   = (const float*)d_in[22];
  const float* bc2   = (const float*)d_in[23];
  float* out = (float*)d_out;

  // workspace layout
  float*    h0   = (float*)d_ws;                        // 6.4M f32
  float*    h1   = h0 + (size_t)N_NODES * 64;           // 6.4M f32
  float*    gsum = h1 + (size_t)N_NODES * 64;           // 32768 f32
  unsigned* gmax = (unsigned*)(gsum + N_GRAPHS * 64);   // 32768
  int*      gcnt = (int*)(gmax + N_GRAPHS * 64);        // 512
  __bf16*   wp   = (__bf16*)(gcnt + 512);               // 3*16384 bf16
  int*      deg  = (int*)(wp + 3 * 16384);              // 100000
  int*      curw = deg + N_NODES;                       // 100000
  int*      rowp = curw + N_NODES;                      // 100001
  int*      bsum = rowp + (N_NODES + 1);                // 391
  int*      boff = bsum + 512;                          // 391
  int*      ssrc = boff + 512;                          // 1.2M

  const int* src = ei;             // edge_index[0]
  const int* dst = ei + N_EDGES;   // edge_index[1]

  const float* epss[3] = {eps1, eps2, eps3};
  const float* Was[3]  = {W1a, W2a, W3a};
  const float* bas[3]  = {b1a, b2a, b3a};
  const float* Wbs[3]  = {W1b, W2b, W3b};
  const float* bbs[3]  = {b1b, b2b, b3b};

  const int NB = (N_NODES + 255) / 256;  // 391 tiles
  const int EB = (N_EDGES + 255) / 256;

  // CSR build (edge list identical for all 3 layers)
  hipMemsetAsync(deg, 0, N_NODES * sizeof(int), stream);
  hist_kernel<<<EB, 256, 0, stream>>>(dst, deg);
  scan_sums_kernel<<<NB, 256, 0, stream>>>(deg, bsum);
  scan_bsums_kernel<<<1, 512, 0, stream>>>(bsum, boff, NB);
  scan_final_kernel<<<NB, 256, 0, stream>>>(deg, boff, rowp, curw);
  fill_csr_kernel<<<EB, 256, 0, stream>>>(src, dst, curw, ssrc);

  init_pool_kernel<<<(N_GRAPHS * 64 + 255) / 256, 256, 0, stream>>>(gsum, gmax, gcnt);
  for (int L = 0; L < 3; ++L)
    convert_w_kernel<<<64, 256, 0, stream>>>(Was[L], Wbs[L],
                                             wp + (size_t)L * 16384,
                                             wp + (size_t)L * 16384 + 8192);
  embed_kernel<<<(N_NODES * 64) / 256, 256, 0, stream>>>(x, W_emb, b_emb, h0);

  float* hbuf[4] = {h0, h1, h0, h1};
  for (int L = 0; L < 3; ++L) {
    gin_fused_kernel<<<(N_NODES + 63) / 64, 256, 0, stream>>>(
        hbuf[L], hbuf[L + 1], rowp, ssrc, epss[L],
        wp + (size_t)L * 16384, bas[L],
        wp + (size_t)L * 16384 + 8192, bbs[L]);
  }

  pool_kernel<<<512, 256, 0, stream>>>(h1, batch, gsum, gmax, gcnt);
  cls_kernel<<<N_GRAPHS, 64, 0, stream>>>(gsum, gmax, gcnt, Wc1, bc1, Wc2, bc2, out);
}